// Round 2
// baseline (193.616 us; speedup 1.0000x reference)
//
#include <hip/hip_runtime.h>
#include <math.h>

// Problem: B=4, N=2048, M=64, L=64, all fp32.
// out[bn,l] = sigmoid( (tr[bn,l]*kr[l]+br[l]) * (kl[l]*S[bn,l] + bl[l]*A[bn]) )
//   S[bn,l] = sum_m nl[bn,m,l]*a[bn,m],  A[bn] = sum_m a[bn,m]
//
// One wave per bn-tile (64x64 floats = 16 KiB). Lane i: rows m = (i>>4)+4k,
// col-group i&15 (float4). Fully coalesced 16 B/lane loads; wave covers
// 1 KiB contiguous per instruction. Memory floor: ~134 MiB / 6.3 TB/s ~= 21 us.
// NOTE: timed dur_us includes ~159 us of harness re-poison fills (2x 512 MiB
// fillBuffer @ ~79 us in rocprof); controllable kernel component ~= 35 us.
// R1: nontemporal load/store hints (pure streaming, read-once/write-once).
// R2: 1-wave blocks, hoisted param loads, all-lane epilogue -> ~flat.
// R3 (this round): persistent waves, 4 bn-tiles per wave, two-buffer
//     software pipeline: issue tile t+1's 16 loads BEFORE computing tile t,
//     so the shuffle-reduce/epilogue tail overlaps next-tile HBM latency and
//     the VMEM issue stream never drains at tile boundaries. Also cuts block
//     count 8192 -> 2048 (less dispatch churn). Buffers are statically
//     indexed via full unroll (rule #20: no runtime-indexed reg arrays).

#define LDIM 64
#define MDIM 64
#define TPW  4   // bn-tiles per wave

typedef float v4f __attribute__((ext_vector_type(4)));

__device__ __forceinline__ void prefetch_tile(
    const float* __restrict__ nl, const float* __restrict__ a,
    const float* __restrict__ tr, int bn, int lane, int row0, int l0,
    v4f (&v)[16], float& a_lane, float4& t)
{
    const float* nlp = nl + (size_t)bn * (MDIM * LDIM);
    a_lane = a[(size_t)bn * MDIM + lane];
    t = *reinterpret_cast<const float4*>(tr + (size_t)bn * LDIM + l0);
#pragma unroll
    for (int k = 0; k < 16; ++k)
        v[k] = __builtin_nontemporal_load(
            reinterpret_cast<const v4f*>(nlp + (row0 + 4 * k) * LDIM + l0));
}

__device__ __forceinline__ void compute_store_tile(
    const v4f (&v)[16], float a_lane, const float4& t,
    const float4& K, const float4& Bl, const float4& Kr, const float4& Br,
    float* __restrict__ out, int bn, int lane, int row0, int l0)
{
    v4f acc = {0.f, 0.f, 0.f, 0.f};
#pragma unroll
    for (int k = 0; k < 16; ++k) {
        const float am = __shfl(a_lane, row0 + 4 * k, 64);
        acc.x = fmaf(am, v[k].x, acc.x);
        acc.y = fmaf(am, v[k].y, acc.y);
        acc.z = fmaf(am, v[k].z, acc.z);
        acc.w = fmaf(am, v[k].w, acc.w);
    }

    // Reduce across the 4 lanes sharing colg (lanes i, i^16, i^32, i^48).
#pragma unroll
    for (int off = 16; off <= 32; off <<= 1) {
        acc.x += __shfl_xor(acc.x, off, 64);
        acc.y += __shfl_xor(acc.y, off, 64);
        acc.z += __shfl_xor(acc.z, off, 64);
        acc.w += __shfl_xor(acc.w, off, 64);
    }

    // Full-wave sum of a[bn,:].
    float asum = a_lane;
#pragma unroll
    for (int off = 1; off <= 32; off <<= 1)
        asum += __shfl_xor(asum, off, 64);

    const float wx = (t.x * Kr.x + Br.x) * (K.x * acc.x + Bl.x * asum);
    const float wy = (t.y * Kr.y + Br.y) * (K.y * acc.y + Bl.y * asum);
    const float wz = (t.z * Kr.z + Br.z) * (K.z * acc.z + Bl.z * asum);
    const float ww = (t.w * Kr.w + Br.w) * (K.w * acc.w + Bl.w * asum);

    v4f o;
    o.x = 1.0f / (1.0f + __expf(-wx));
    o.y = 1.0f / (1.0f + __expf(-wy));
    o.z = 1.0f / (1.0f + __expf(-wz));
    o.w = 1.0f / (1.0f + __expf(-ww));

    if (lane < 16) {
        __builtin_nontemporal_store(
            o, reinterpret_cast<v4f*>(out + (size_t)bn * LDIM + l0));
    }
}

__global__ __launch_bounds__(64) void slg_fused_kernel(
    const float* __restrict__ tr,   // (BN, L)
    const float* __restrict__ nl,   // (BN, M, L)
    const float* __restrict__ a,    // (BN, M)
    const float* __restrict__ kl,   // (L)
    const float* __restrict__ bl,   // (L)
    const float* __restrict__ kr,   // (L)
    const float* __restrict__ br,   // (L)
    float* __restrict__ out,        // (BN, L)
    int BN)
{
    const int wid    = blockIdx.x;        // one wave per block
    const int stride = gridDim.x;         // BN / TPW
    const int lane = threadIdx.x & 63;
    const int colg = lane & 15;
    const int row0 = lane >> 4;
    const int l0 = colg * 4;

    // Tile-invariant per-feature params (all lanes; lines alias -> no extra HBM).
    const float4 K  = *reinterpret_cast<const float4*>(kl + l0);
    const float4 Bl = *reinterpret_cast<const float4*>(bl + l0);
    const float4 Kr = *reinterpret_cast<const float4*>(kr + l0);
    const float4 Br = *reinterpret_cast<const float4*>(br + l0);

    v4f vA[16], vB[16];
    float aA = 0.f, aB = 0.f;
    float4 tA = {0,0,0,0}, tB = {0,0,0,0};

    // Prologue: prefetch tile 0 into buffer A.
    if (wid < BN)
        prefetch_tile(nl, a, tr, wid, lane, row0, l0, vA, aA, tA);

    // Pipeline: issue tile t+1's loads, THEN compute tile t. The reduce +
    // epilogue of tile t runs while tile t+1's 16 KiB is in flight.
#pragma unroll
    for (int t = 0; t < TPW; ++t) {
        const int bn  = wid + t * stride;
        const int bnn = bn + stride;
        if ((t & 1) == 0) {
            if (t + 1 < TPW && bnn < BN)
                prefetch_tile(nl, a, tr, bnn, lane, row0, l0, vB, aB, tB);
            if (bn < BN)
                compute_store_tile(vA, aA, tA, K, Bl, Kr, Br, out, bn, lane, row0, l0);
        } else {
            if (t + 1 < TPW && bnn < BN)
                prefetch_tile(nl, a, tr, bnn, lane, row0, l0, vA, aA, tA);
            if (bn < BN)
                compute_store_tile(vB, aB, tB, K, Bl, Kr, Br, out, bn, lane, row0, l0);
        }
    }
}

extern "C" void kernel_launch(void* const* d_in, const int* in_sizes, int n_in,
                              void* d_out, int out_size, void* d_ws, size_t ws_size,
                              hipStream_t stream) {
    const float* tr = (const float*)d_in[0];  // (B,N,L)
    const float* nl = (const float*)d_in[1];  // (B,N,M,L)
    const float* a  = (const float*)d_in[2];  // (B,N,M)
    const float* kl = (const float*)d_in[3];  // (L)
    const float* bl = (const float*)d_in[4];  // (L)
    const float* kr = (const float*)d_in[5];  // (L)
    const float* br = (const float*)d_in[6];  // (L)
    float* out = (float*)d_out;

    const int BN = in_sizes[0] / LDIM;        // B*N = 8192
    const int block = 64;                     // 1 wave per block
    const int grid = (BN + TPW - 1) / TPW;    // 2048 persistent waves

    slg_fused_kernel<<<grid, block, 0, stream>>>(tr, nl, a, kl, bl, kr, br, out, BN);
}